// Round 3
// baseline (57.843 us; speedup 1.0000x reference)
//
#include <hip/hip_runtime.h>

// Problem constants
#define NJ       21
#define CH       3380      // floats per 64-split channel within a batch (26*26*5)
#define BSTRIDE  216320    // floats per batch (64*3380)
#define GPB      845       // float2-groups per block (half of 1690)
#define TPB      896       // threads per block (14 waves)
#define NBLK     512       // 256 batches * 2 blocks

#define CA0 (1920.0f / 26.0f)
#define CA1 (1080.0f / 26.0f)
#define CA2 (1000.0f / 5.0f)
#define INVC0 0.15651764f   // 1/(e^2 - 1)

__device__ __forceinline__ float sigmoidf_(float x) {
    return 1.0f / (1.0f + __expf(-x));
}

// block = (batch b, half c): covers float2-groups [c*845, (c+1)*845) of batch b.
// Per channel each block streams 6.76 KB contiguous (threads are consecutive).
__global__ __launch_bounds__(TPB, 7) void hpo_main(
    const float* __restrict__ pred,
    const float* __restrict__ gt,
    float* __restrict__ partial,
    int*   __restrict__ counter,
    float* __restrict__ out)
{
    __shared__ float s_gs[NJ][3];   // gt * scale
    __shared__ float s_tv[NJ][3];   // target_uvd values at the GT cell
    __shared__ int   s_lin_sh;
    __shared__ float s_w[TPB / 64];
    __shared__ int   s_last;

    const int bid  = blockIdx.x;
    const int b    = bid >> 1;      // batch
    const int c    = bid & 1;       // half within batch
    const int tid  = threadIdx.x;
    const int lane = tid & 63;
    const int wid  = tid >> 6;

    const float* gtb = gt + b * (NJ * 3);

    if (tid < NJ * 3) {
        const int j = tid / 3;
        const int a = tid - 3 * j;
        const float scale_a = (a == 0) ? 1920.0f : ((a == 1) ? 1080.0f : 1000.0f);
        const float dim_a   = (a == 2) ? 5.0f : 26.0f;
        const int   dimi    = (a == 2) ? 5 : 26;
        const float gv = gtb[tid];
        s_gs[j][a] = gv * scale_a;
        // gidx comes from joint 0 (HAND_ROOT) only
        const float g0v = gtb[a];
        int gi = (int)(g0v * dim_a);
        gi = min(max(gi, 0), dimi - 1);
        s_tv[j][a] = gv * dim_a - (float)gi;
    }
    if (tid == 0) {
        int gi = min(max((int)(gtb[0] * 26.0f), 0), 25);
        int gj = min(max((int)(gtb[1] * 26.0f), 0), 25);
        int gk = min(max((int)(gtb[2] * 5.0f),  0), 4);
        s_lin_sh = 130 * gi + 5 * gj + gk;
    }
    __syncthreads();

    const int s_lin = s_lin_sh;
    float acc = 0.0f;

    if (tid < GPB) {
        const int t  = c * GPB + tid;
        const int g0 = 2 * t;
        const float* base = pred + (size_t)b * BSTRIDE + g0;

        // per-cell constants: cell_coord * (scale/dim)
        float cb0[2], cb1[2], cb2[2];
#pragma unroll
        for (int k = 0; k < 2; ++k) {
            const int g   = g0 + k;
            const int w   = g / 130;
            const int rem = g - w * 130;
            const int h   = rem / 5;
            const int d   = rem - h * 5;
            cb0[k] = (float)w * CA0;
            cb1[k] = (float)h * CA1;
            cb2[k] = (float)d * CA2;
        }

        const int klin = s_lin - g0;   // in [0,2) iff this thread owns the GT cell

        float csum[2] = {0.0f, 0.0f};

        // depth-1 prefetch pipeline over joints
        float2 x = *(const float2*)(base);
        float2 y = *(const float2*)(base + CH);
        float2 z = *(const float2*)(base + 2 * CH);

#pragma unroll 3
        for (int j = 0; j < NJ; ++j) {
            const int jn = (j < NJ - 1) ? j + 1 : j;
            const float* pn = base + (size_t)(3 * jn) * CH;
            const float2 nx = *(const float2*)(pn);
            const float2 ny = *(const float2*)(pn + CH);
            const float2 nz = *(const float2*)(pn + 2 * CH);

            float xv[2] = {x.x, x.y};
            float yv[2] = {y.x, y.y};
            float zv[2] = {z.x, z.y};
            if (j == 0) {
#pragma unroll
                for (int k = 0; k < 2; ++k) {
                    xv[k] = sigmoidf_(xv[k]);
                    yv[k] = sigmoidf_(yv[k]);
                    zv[k] = sigmoidf_(zv[k]);
                }
            }
            const float gs0 = s_gs[j][0], gs1 = s_gs[j][1], gs2 = s_gs[j][2];
#pragma unroll
            for (int k = 0; k < 2; ++k) {
                const float d0 = fmaf(xv[k], CA0, cb0[k] - gs0);
                const float d1 = fmaf(yv[k], CA1, cb1[k] - gs1);
                const float d2 = fmaf(zv[k], CA2, cb2[k] - gs2);
                const float dsq = fmaf(d0, d0, fmaf(d1, d1, fmaf(d2, d2, 1e-5f)));
                const float dist = sqrtf(dsq);
                const float cv = (__expf(2.0f - dist * (2.0f / 75.0f)) - 1.0f) * INVC0;
                csum[k] += (dist < 75.0f) ? cv : 0.0f;
            }
            x = nx; y = ny; z = nz;
        }

        // ---- conf loss (channel 63) ----
        {
            const float2 wc = *(const float2*)(base + (size_t)63 * CH);
            const float wv[2] = {wc.x, wc.y};
#pragma unroll
            for (int k = 0; k < 2; ++k) {
                const float mc = csum[k] * (1.0f / 21.0f);
                const float pconf = sigmoidf_(wv[k]);
                const bool  il = (k == klin);
                const float cm2 = il ? 5.0f : ((mc > 0.6f) ? 0.0f : 0.1f);
                const float tc  = il ? mc : 0.0f;
                const float dd  = pconf - tc;
                acc += 0.5f * cm2 * dd * dd;
            }
        }

        // ---- u/v/d losses: only the GT cell contributes (onehot mask) ----
        if ((unsigned)klin < 2u) {
            const float* p = pred + (size_t)b * BSTRIDE + s_lin;
#pragma unroll
            for (int j = 0; j < NJ; ++j) {
#pragma unroll
                for (int a = 0; a < 3; ++a) {
                    float v = p[(size_t)(3 * j + a) * CH];
                    if (j == 0) v = sigmoidf_(v);
                    const float d = v - s_tv[j][a];
                    acc += 0.5f * d * d;
                }
            }
        }
    }

    // ---- wave reduction, then block reduction over 14 waves ----
#pragma unroll
    for (int m = 32; m > 0; m >>= 1) acc += __shfl_xor(acc, m, 64);
    if (lane == 0) s_w[wid] = acc;
    __syncthreads();

    if (tid == 0) {
        float s = 0.0f;
#pragma unroll
        for (int i = 0; i < TPB / 64; ++i) s += s_w[i];
        partial[bid] = s;
        __threadfence();
        const int old = atomicAdd(counter, 1);
        s_last = (old == NBLK - 1) ? 1 : 0;
    }
    __syncthreads();

    // ---- last block folds the 512 partials (deterministic index order) ----
    if (s_last && tid < 64) {
        __threadfence();
        float a = 0.0f;
#pragma unroll
        for (int i = 0; i < NBLK / 64; ++i) a += partial[tid + 64 * i];
#pragma unroll
        for (int m = 32; m > 0; m >>= 1) a += __shfl_xor(a, m, 64);
        if (tid == 0) out[0] = a;
    }
}

extern "C" void kernel_launch(void* const* d_in, const int* in_sizes, int n_in,
                              void* d_out, int out_size, void* d_ws, size_t ws_size,
                              hipStream_t stream) {
    const float* pred = (const float*)d_in[0];
    const float* gt   = (const float*)d_in[1];
    float* out        = (float*)d_out;

    int*   counter = (int*)d_ws;                        // 1 int at ws+0
    float* partial = (float*)((char*)d_ws + 256);       // 512 floats at ws+256

    hipMemsetAsync(d_ws, 0, 256, stream);               // zero the counter
    hpo_main<<<NBLK, TPB, 0, stream>>>(pred, gt, partial, counter, out);
}